// Round 1
// baseline (946.297 us; speedup 1.0000x reference)
//
#include <hip/hip_runtime.h>
#include <hip/hip_bf16.h>

// LambdaConv1d: B=16, C=512, N=4096, h=4, k=16, u=4, v=128, m=7
// Round 0: all-f32 correct baseline.
//   K0 pack:   Wall(640x512)=[Wq;Wk;Wv], per-row scale/bias (BN fold; keys raw)
//   K1 gemm:   proj[b,o,n] = sum_c Wall[o,c]*x[b,c,n], epilogue y*s+b   (dominant)
//   K2 softmax: rows 64..127 of proj, over N (in-place)
//   K3 lambda_c[b,kk,vv] = sum_{ui,n} keys[kk*4+ui,n]*P[vv*4+ui,n]  (atomic n-split)
//   K4 final:  y = y_c + y_p with y_p reordered: A[h,ui,dm,n]=sum_k q*emb;
//              y_p = sum_{ui,dm} A * P2[ui,vv,n-3+dm]  (avoids 536MB lambda_p)

#define B_  16
#define C_  512
#define N_  4096
#define OT  640   // 64 q rows + 64 key rows + 512 value rows

static constexpr size_t PROJ_ELEMS = (size_t)B_ * OT * N_;        // 41,943,040 f32
static constexpr size_t WALL_OFF   = PROJ_ELEMS;
static constexpr size_t SB_OFF     = WALL_OFF + (size_t)OT * C_;  // +327,680
static constexpr size_t LAM_OFF    = SB_OFF + (size_t)OT * 2;     // +1,280
// total ws: LAM_OFF + 16*16*128 floats  (~169.3 MB)

// ---------------------------------------------------------------- K0: pack
__global__ __launch_bounds__(256) void pack_kernel(
    const float* __restrict__ Wq, const float* __restrict__ gq, const float* __restrict__ bq,
    const float* __restrict__ Wk, const float* __restrict__ Wv,
    const float* __restrict__ gv, const float* __restrict__ bv,
    float* __restrict__ Wall, float* __restrict__ sb) {
  int idx = blockIdx.x * 256 + threadIdx.x;
  if (idx < OT * C_) {
    int row = idx >> 9;  // /512
    float val;
    if (row < 64)        val = Wq[idx];
    else if (row < 128)  val = Wk[idx - 64 * C_];
    else                 val = Wv[idx - 128 * C_];
    Wall[idx] = val;
  }
  if (idx < OT) {
    // scale = gamma / sqrt(1 + 1e-5) ; keys rows raw
    const float inv = 0.99999500003749971875f;
    float s, bi;
    if (idx < 64)       { s = gq[idx] * inv;       bi = bq[idx]; }
    else if (idx < 128) { s = 1.0f;                bi = 0.0f; }
    else                { s = gv[idx - 128] * inv; bi = bv[idx - 128]; }
    sb[idx * 2]     = s;
    sb[idx * 2 + 1] = bi;
  }
}

// ---------------------------------------------------------------- K1: proj GEMM (f32)
// grid: (N/64, OT/64, B), 256 threads, BK=16, 4x4 microtile per thread
__global__ __launch_bounds__(256) void gemm_proj(
    const float* __restrict__ x, const float* __restrict__ Wall,
    const float* __restrict__ sb, float* __restrict__ proj) {
  const int t  = threadIdx.x;
  const int bn = blockIdx.x;
  const int bm = blockIdx.y;
  const int b  = blockIdx.z;
  const float* xb = x + (size_t)b * C_ * N_;
  float* pb = proj + (size_t)b * OT * N_;

  __shared__ float a_lds[16][64];  // [k][o]
  __shared__ float b_lds[16][64];  // [k][n]

  const int oo = (t & 15) * 4;
  const int nn = (t >> 4) * 4;
  const int arow = t >> 2, ac4 = (t & 3) * 4;
  const int brow = t >> 4, bc4 = (t & 15) * 4;

  float acc[4][4] = {};

  for (int c0 = 0; c0 < C_; c0 += 16) {
    float4 av = *(const float4*)&Wall[(size_t)(bm * 64 + arow) * C_ + c0 + ac4];
    float4 bv = *(const float4*)&xb[(size_t)(c0 + brow) * N_ + bn * 64 + bc4];
    __syncthreads();
    a_lds[ac4 + 0][arow] = av.x;
    a_lds[ac4 + 1][arow] = av.y;
    a_lds[ac4 + 2][arow] = av.z;
    a_lds[ac4 + 3][arow] = av.w;
    *(float4*)&b_lds[brow][bc4] = bv;
    __syncthreads();
#pragma unroll
    for (int kk = 0; kk < 16; ++kk) {
      float4 a4 = *(const float4*)&a_lds[kk][oo];
      float4 b4 = *(const float4*)&b_lds[kk][nn];
      acc[0][0] += a4.x * b4.x; acc[0][1] += a4.x * b4.y; acc[0][2] += a4.x * b4.z; acc[0][3] += a4.x * b4.w;
      acc[1][0] += a4.y * b4.x; acc[1][1] += a4.y * b4.y; acc[1][2] += a4.y * b4.z; acc[1][3] += a4.y * b4.w;
      acc[2][0] += a4.z * b4.x; acc[2][1] += a4.z * b4.y; acc[2][2] += a4.z * b4.z; acc[2][3] += a4.z * b4.w;
      acc[3][0] += a4.w * b4.x; acc[3][1] += a4.w * b4.y; acc[3][2] += a4.w * b4.z; acc[3][3] += a4.w * b4.w;
    }
  }
#pragma unroll
  for (int i = 0; i < 4; ++i) {
    int row = bm * 64 + oo + i;
    float s = sb[row * 2], bi = sb[row * 2 + 1];
    float4 r;
    r.x = acc[i][0] * s + bi;
    r.y = acc[i][1] * s + bi;
    r.z = acc[i][2] * s + bi;
    r.w = acc[i][3] * s + bi;
    *(float4*)&pb[(size_t)row * N_ + bn * 64 + nn] = r;
  }
}

// ---------------------------------------------------------------- K2: keys softmax over N
// grid: (64, B), one block per key row
__global__ __launch_bounds__(256) void softmax_keys(float* __restrict__ proj) {
  const int r = blockIdx.x, b = blockIdx.y;
  float* row = proj + ((size_t)b * OT + 64 + r) * N_;
  const int t = threadIdx.x;
  float4 v[4];
  float mx = -1e30f;
#pragma unroll
  for (int i = 0; i < 4; ++i) {
    v[i] = ((const float4*)row)[t + i * 256];
    mx = fmaxf(mx, fmaxf(fmaxf(v[i].x, v[i].y), fmaxf(v[i].z, v[i].w)));
  }
  __shared__ float red[4];
#pragma unroll
  for (int off = 32; off; off >>= 1) mx = fmaxf(mx, __shfl_xor(mx, off));
  if ((t & 63) == 0) red[t >> 6] = mx;
  __syncthreads();
  mx = fmaxf(fmaxf(red[0], red[1]), fmaxf(red[2], red[3]));
  float sum = 0.f;
#pragma unroll
  for (int i = 0; i < 4; ++i) {
    v[i].x = __expf(v[i].x - mx);
    v[i].y = __expf(v[i].y - mx);
    v[i].z = __expf(v[i].z - mx);
    v[i].w = __expf(v[i].w - mx);
    sum += v[i].x + v[i].y + v[i].z + v[i].w;
  }
  __syncthreads();
#pragma unroll
  for (int off = 32; off; off >>= 1) sum += __shfl_xor(sum, off);
  if ((t & 63) == 0) red[t >> 6] = sum;
  __syncthreads();
  float invs = 1.0f / (red[0] + red[1] + red[2] + red[3]);
#pragma unroll
  for (int i = 0; i < 4; ++i) {
    v[i].x *= invs; v[i].y *= invs; v[i].z *= invs; v[i].w *= invs;
    ((float4*)row)[t + i * 256] = v[i];
  }
}

// ---------------------------------------------------------------- K3: lambda_c
// grid: (16 n-splits, B); NC=256; keys chunk in LDS; atomicAdd partials
__global__ __launch_bounds__(256) void lambda_c_kernel(
    const float* __restrict__ proj, float* __restrict__ lam) {
  const int b = blockIdx.y;
  const int n0 = blockIdx.x * 256;
  const float* pb = proj + (size_t)b * OT * N_;
  __shared__ float keys_lds[64][256];
  const int t = threadIdx.x;
#pragma unroll
  for (int i = 0; i < 16; ++i) {
    int task = i * 256 + t;             // 4096 float4 tasks
    int r = task >> 6, c4 = (task & 63) * 4;
    *(float4*)&keys_lds[r][c4] = *(const float4*)&pb[(size_t)(64 + r) * N_ + n0 + c4];
  }
  __syncthreads();
  const int l = t & 63, w = t >> 6;
  float* lamb = lam + (size_t)b * 16 * 128;
  for (int vv = w * 32; vv < w * 32 + 32; ++vv) {
    float acc[16];
#pragma unroll
    for (int kk = 0; kk < 16; ++kk) acc[kk] = 0.f;
#pragma unroll
    for (int ui = 0; ui < 4; ++ui) {
      const float* prow = &pb[(size_t)(128 + vv * 4 + ui) * N_ + n0];
#pragma unroll
      for (int ns = 0; ns < 4; ++ns) {
        float pv = prow[ns * 64 + l];
#pragma unroll
        for (int kk = 0; kk < 16; ++kk)
          acc[kk] += pv * keys_lds[kk * 4 + ui][ns * 64 + l];
      }
    }
#pragma unroll
    for (int kk = 0; kk < 16; ++kk) {
      float vsum = acc[kk];
#pragma unroll
      for (int off = 32; off; off >>= 1) vsum += __shfl_xor(vsum, off);
      if (l == 0) atomicAdd(&lamb[kk * 128 + vv], vsum);
    }
  }
}

// ---------------------------------------------------------------- K4: final fused y_c + y_p
// grid: (N/32, 2 vv-halves, B); LDS ~68KB
__global__ __launch_bounds__(256) void final_kernel(
    const float* __restrict__ proj, const float* __restrict__ lam,
    const float* __restrict__ emb, float* __restrict__ out) {
  const int n0  = blockIdx.x * 32;
  const int vh  = blockIdx.y;
  const int b   = blockIdx.z;
  const int vv0 = vh * 64;
  const float* pb = proj + (size_t)b * OT * N_;
  const int t = threadIdx.x;

  __shared__ float q_lds[64][32];     // q rows x n-chunk
  __shared__ float P_lds[256][40];    // (ui,vl) rows x (n-chunk + 8 halo)
  __shared__ float A_lds[112][32];    // (h,ui,dm) x n-chunk
  __shared__ float lam_lds[16][64];
  __shared__ float emb_lds[448];

  // q: 64x32 = 512 float4 tasks
#pragma unroll
  for (int i = 0; i < 2; ++i) {
    int task = i * 256 + t;
    int r = task >> 3, c4 = (task & 7) * 4;
    *(float4*)&q_lds[r][c4] = *(const float4*)&pb[(size_t)r * N_ + n0 + c4];
  }
  // lambda half: 16x64 = 256 float4 tasks
  {
    int r = t >> 4, c4 = (t & 15) * 4;
    *(float4*)&lam_lds[r][c4] = *(const float4*)&lam[((size_t)b * 16 + r) * 128 + vv0 + c4];
  }
  for (int i = t; i < 448; i += 256) emb_lds[i] = emb[i];
  // P: 256 rows x 40 cols (halo 4 each side), zero-padded at edges
#pragma unroll
  for (int i = 0; i < 10; ++i) {
    int task = i * 256 + t;             // 2560 float4 tasks
    int r = task / 10;
    int c4g = task - r * 10;
    int gn = n0 - 4 + c4g * 4;
    float4 val = make_float4(0.f, 0.f, 0.f, 0.f);
    if (gn >= 0 && gn < N_)
      val = *(const float4*)&pb[(size_t)(128 + (r >> 6) * 128 + vv0 + (r & 63)) * N_ + gn];
    *(float4*)&P_lds[r][c4g * 4] = val;
  }
  __syncthreads();

  // A[h,ui,dm][nl] = sum_k q[h*16+k][nl] * emb[k,ui,dm]  (3584 tasks)
#pragma unroll
  for (int i = 0; i < 14; ++i) {
    int task = i * 256 + t;
    int aidx = task % 112;
    int nl   = task / 112;
    int hh = aidx / 28, rem = aidx - hh * 28;
    float s = 0.f;
#pragma unroll
    for (int kk = 0; kk < 16; ++kk)
      s += q_lds[hh * 16 + kk][nl] * emb_lds[kk * 28 + rem];
    A_lds[aidx][nl] = s;
  }
  __syncthreads();

  const int nl = t & 31, pg = t >> 5;
  const int hh = pg >> 1;
  float qreg[16], areg[28];
#pragma unroll
  for (int kk = 0; kk < 16; ++kk) qreg[kk] = q_lds[hh * 16 + kk][nl];
#pragma unroll
  for (int r = 0; r < 28; ++r) areg[r] = A_lds[hh * 28 + r][nl];
  float* ob = out + ((size_t)b * 512 + hh * 128 + vv0) * N_ + n0;
#pragma unroll
  for (int ii = 0; ii < 32; ++ii) {
    int vl = (pg & 1) * 32 + ii;
    float y = 0.f;
#pragma unroll
    for (int kk = 0; kk < 16; ++kk) y += qreg[kk] * lam_lds[kk][vl];
#pragma unroll
    for (int ui = 0; ui < 4; ++ui)
#pragma unroll
      for (int dm = 0; dm < 7; ++dm)
        y += areg[ui * 7 + dm] * P_lds[ui * 64 + vl][nl + dm + 1];
    ob[(size_t)vl * N_ + nl] = y;
  }
}

// ---------------------------------------------------------------- launch
extern "C" void kernel_launch(void* const* d_in, const int* in_sizes, int n_in,
                              void* d_out, int out_size, void* d_ws, size_t ws_size,
                              hipStream_t stream) {
  const float* x   = (const float*)d_in[0];
  const float* Wq  = (const float*)d_in[1];
  const float* gq  = (const float*)d_in[2];
  const float* bq  = (const float*)d_in[3];
  const float* Wk  = (const float*)d_in[4];
  const float* Wv  = (const float*)d_in[5];
  const float* gv  = (const float*)d_in[6];
  const float* bv  = (const float*)d_in[7];
  const float* emb = (const float*)d_in[8];

  float* ws   = (float*)d_ws;
  float* proj = ws;
  float* Wall = ws + WALL_OFF;
  float* sb   = ws + SB_OFF;
  float* lam  = ws + LAM_OFF;
  float* out  = (float*)d_out;

  hipMemsetAsync(lam, 0, (size_t)B_ * 16 * 128 * sizeof(float), stream);
  pack_kernel<<<dim3(1280), 256, 0, stream>>>(Wq, gq, bq, Wk, Wv, gv, bv, Wall, sb);
  gemm_proj<<<dim3(N_ / 64, OT / 64, B_), 256, 0, stream>>>(x, Wall, sb, proj);
  softmax_keys<<<dim3(64, B_), 256, 0, stream>>>(proj);
  lambda_c_kernel<<<dim3(16, B_), 256, 0, stream>>>(proj, lam);
  final_kernel<<<dim3(N_ / 32, 2, B_), 256, 0, stream>>>(proj, lam, emb, out);
}

// Round 2
// 518.758 us; speedup vs baseline: 1.8242x; 1.8242x over previous
//
#include <hip/hip_runtime.h>
#include <hip/hip_bf16.h>

// LambdaConv1d: B=16, C=512, N=4096, h=4, k=16, u=4, v=128, m=7
// R1: projection GEMM -> bf16 MFMA (m97 structure: 128^2 tile, BK=32,
//     global_load_lds width=16, B^T operand layout via transposed x).
//   K0  pack:    Wall_bf(640x512 bf16)=[Wq;Wk;Wv], per-row scale/bias f32
//   K0b convert: x (B,C,N) f32 -> xT (B,N,C) bf16  (LDS-tiled transpose)
//   K1  gemm_mfma: proj[b,o,n] = sum_c W[o,c]*xT[b,n,c], epilogue y*s+b (f32 out)
//   K2  softmax keys rows over N (in-place, f32)
//   K3  lambda_c (f32)
//   K4  final fused y_c + y_p (f32)

#define B_  16
#define C_  512
#define N_  4096
#define OT  640   // 64 q rows + 64 key rows + 512 value rows

typedef __bf16 bf16x8 __attribute__((ext_vector_type(8)));
typedef float  f32x4  __attribute__((ext_vector_type(4)));

// ws layout (float offsets)
static constexpr size_t PROJ_ELEMS = (size_t)B_ * OT * N_;           // 41,943,040 f32
static constexpr size_t XT_OFF     = PROJ_ELEMS;                     // bf16 x (B*N*C) = 16,777,216 floats
static constexpr size_t WB_OFF     = XT_OFF + ((size_t)B_ * N_ * C_) / 2;
static constexpr size_t SB_OFF     = WB_OFF + ((size_t)OT * C_) / 2; // Wall_bf = 163,840 floats
static constexpr size_t LAM_OFF    = SB_OFF + (size_t)OT * 2;
// total: LAM_OFF + 16*16*128 floats  (~235.7 MB)

__device__ __forceinline__ void load_lds16(const void* g, void* l) {
  __builtin_amdgcn_global_load_lds(
      (const __attribute__((address_space(1))) void*)g,
      (__attribute__((address_space(3))) void*)l, 16, 0, 0);
}

// ---------------------------------------------------------------- K0: pack (W -> bf16, sb f32)
__global__ __launch_bounds__(256) void pack_kernel(
    const float* __restrict__ Wq, const float* __restrict__ gq, const float* __restrict__ bq,
    const float* __restrict__ Wk, const float* __restrict__ Wv,
    const float* __restrict__ gv, const float* __restrict__ bv,
    __hip_bfloat16* __restrict__ Wall, float* __restrict__ sb) {
  int idx = blockIdx.x * 256 + threadIdx.x;
  if (idx < OT * C_) {
    int row = idx >> 9;  // /512
    float val;
    if (row < 64)        val = Wq[idx];
    else if (row < 128)  val = Wk[idx - 64 * C_];
    else                 val = Wv[idx - 128 * C_];
    Wall[idx] = __float2bfloat16(val);
  }
  if (idx < OT) {
    const float inv = 0.99999500003749971875f;  // 1/sqrt(1+1e-5)
    float s, bi;
    if (idx < 64)       { s = gq[idx] * inv;       bi = bq[idx]; }
    else if (idx < 128) { s = 1.0f;                bi = 0.0f; }
    else                { s = gv[idx - 128] * inv; bi = bv[idx - 128]; }
    sb[idx * 2]     = s;
    sb[idx * 2 + 1] = bi;
  }
}

// ---------------------------------------------------------------- K0b: x -> xT bf16 (B,N,C)
// grid (N/64, C/64, B), 256 thr; 64x64 f32 LDS tile (pad 65)
__global__ __launch_bounds__(256) void convert_x(
    const float* __restrict__ x, __hip_bfloat16* __restrict__ xT) {
  const int n0 = blockIdx.x * 64;
  const int c0 = blockIdx.y * 64;
  const int b  = blockIdx.z;
  __shared__ float tile[64][65];
  const int t = threadIdx.x;
  const int tr = t >> 4, tc4 = (t & 15) * 4;
  const float* xb = x + ((size_t)b * C_ + c0) * N_ + n0;
#pragma unroll
  for (int i = 0; i < 4; ++i) {
    float4 v = *(const float4*)&xb[(size_t)(i * 16 + tr) * N_ + tc4];
    *(float4*)&tile[i * 16 + tr][tc4] = v;
  }
  __syncthreads();
  __hip_bfloat16* ob = xT + ((size_t)b * N_ + n0) * C_ + c0;
#pragma unroll
  for (int i = 0; i < 4; ++i) {
    int rn = i * 16 + tr;
    uint2 pk;
    __hip_bfloat16* ph = (__hip_bfloat16*)&pk;
#pragma unroll
    for (int j = 0; j < 4; ++j) ph[j] = __float2bfloat16(tile[tc4 + j][rn]);
    *(uint2*)&ob[(size_t)rn * C_ + tc4] = pk;
  }
}

// ---------------------------------------------------------------- K1: MFMA proj GEMM
// A = Wall_bf (640x512 row-major), B = xT (per-batch 4096x512 row-major = B^T layout)
// grid (N/128, OT/128, B), 256 thr = 4 waves (2x2), each wave 64x64 out.
__global__ __launch_bounds__(256) void gemm_mfma(
    const __hip_bfloat16* __restrict__ xT, const __hip_bfloat16* __restrict__ Wb,
    const float* __restrict__ sb, float* __restrict__ proj) {
  const int t = threadIdx.x;
  const int l = t & 63, w = t >> 6;
  const int wr = w >> 1, wc = w & 1;
  const int m0 = blockIdx.y * 128, n0 = blockIdx.x * 128;
  const int b = blockIdx.z;
  const __hip_bfloat16* xb = xT + (size_t)b * N_ * C_;

  __shared__ __hip_bfloat16 Als[128 * 32];  // [m][k] row-major
  __shared__ __hip_bfloat16 Bls[128 * 32];  // [n][k] row-major

  // staging: LDS elem off = i*2048 + w*512 + l*8 -> row = i*64 + w*16 + (l>>2), col=(l&3)*8
  const int srow = w * 16 + (l >> 2);
  const int scol = (l & 3) * 8;
  const __hip_bfloat16* gA = Wb + (size_t)(m0 + srow) * C_ + scol;
  const __hip_bfloat16* gB = xb + (size_t)(n0 + srow) * C_ + scol;
  __hip_bfloat16* lA = &Als[w * 512 + l * 8];
  __hip_bfloat16* lB = &Bls[w * 512 + l * 8];

  const int fr = l & 15;         // fragment row
  const int kg = (l >> 4) * 8;   // k-group

  f32x4 acc[4][4] = {};

  for (int c0 = 0; c0 < C_; c0 += 32) {
    __syncthreads();  // previous reads done before overwrite
#pragma unroll
    for (int i = 0; i < 2; ++i) {
      load_lds16(gA + (size_t)i * 64 * C_ + c0, lA + i * 2048);
      load_lds16(gB + (size_t)i * 64 * C_ + c0, lB + i * 2048);
    }
    __syncthreads();  // compiler drains vmcnt(0) before s_barrier
    bf16x8 af[4], bfr[4];
#pragma unroll
    for (int m = 0; m < 4; ++m)
      af[m] = *(const bf16x8*)&Als[(size_t)(wr * 64 + m * 16 + fr) * 32 + kg];
#pragma unroll
    for (int n = 0; n < 4; ++n)
      bfr[n] = *(const bf16x8*)&Bls[(size_t)(wc * 64 + n * 16 + fr) * 32 + kg];
#pragma unroll
    for (int m = 0; m < 4; ++m)
#pragma unroll
      for (int n = 0; n < 4; ++n)
        acc[m][n] = __builtin_amdgcn_mfma_f32_16x16x32_bf16(af[m], bfr[n], acc[m][n], 0, 0, 0);
  }

  // epilogue: D row=(l>>4)*4+r, col=l&15 (m89-verified)
  float* pb = proj + (size_t)b * OT * N_;
  const int rb = (l >> 4) * 4;
#pragma unroll
  for (int m = 0; m < 4; ++m) {
#pragma unroll
    for (int r = 0; r < 4; ++r) {
      int grow = m0 + wr * 64 + m * 16 + rb + r;
      float s = sb[grow * 2], bi = sb[grow * 2 + 1];
#pragma unroll
      for (int n = 0; n < 4; ++n) {
        int gcol = n0 + wc * 64 + n * 16 + fr;
        pb[(size_t)grow * N_ + gcol] = acc[m][n][r] * s + bi;
      }
    }
  }
}

// ---------------------------------------------------------------- K2: keys softmax over N
__global__ __launch_bounds__(256) void softmax_keys(float* __restrict__ proj) {
  const int r = blockIdx.x, b = blockIdx.y;
  float* row = proj + ((size_t)b * OT + 64 + r) * N_;
  const int t = threadIdx.x;
  float4 v[4];
  float mx = -1e30f;
#pragma unroll
  for (int i = 0; i < 4; ++i) {
    v[i] = ((const float4*)row)[t + i * 256];
    mx = fmaxf(mx, fmaxf(fmaxf(v[i].x, v[i].y), fmaxf(v[i].z, v[i].w)));
  }
  __shared__ float red[4];
#pragma unroll
  for (int off = 32; off; off >>= 1) mx = fmaxf(mx, __shfl_xor(mx, off));
  if ((t & 63) == 0) red[t >> 6] = mx;
  __syncthreads();
  mx = fmaxf(fmaxf(red[0], red[1]), fmaxf(red[2], red[3]));
  float sum = 0.f;
#pragma unroll
  for (int i = 0; i < 4; ++i) {
    v[i].x = __expf(v[i].x - mx);
    v[i].y = __expf(v[i].y - mx);
    v[i].z = __expf(v[i].z - mx);
    v[i].w = __expf(v[i].w - mx);
    sum += v[i].x + v[i].y + v[i].z + v[i].w;
  }
  __syncthreads();
#pragma unroll
  for (int off = 32; off; off >>= 1) sum += __shfl_xor(sum, off);
  if ((t & 63) == 0) red[t >> 6] = sum;
  __syncthreads();
  float invs = 1.0f / (red[0] + red[1] + red[2] + red[3]);
#pragma unroll
  for (int i = 0; i < 4; ++i) {
    v[i].x *= invs; v[i].y *= invs; v[i].z *= invs; v[i].w *= invs;
    ((float4*)row)[t + i * 256] = v[i];
  }
}

// ---------------------------------------------------------------- K3: lambda_c
__global__ __launch_bounds__(256) void lambda_c_kernel(
    const float* __restrict__ proj, float* __restrict__ lam) {
  const int b = blockIdx.y;
  const int n0 = blockIdx.x * 256;
  const float* pb = proj + (size_t)b * OT * N_;
  __shared__ float keys_lds[64][256];
  const int t = threadIdx.x;
#pragma unroll
  for (int i = 0; i < 16; ++i) {
    int task = i * 256 + t;
    int r = task >> 6, c4 = (task & 63) * 4;
    *(float4*)&keys_lds[r][c4] = *(const float4*)&pb[(size_t)(64 + r) * N_ + n0 + c4];
  }
  __syncthreads();
  const int l = t & 63, w = t >> 6;
  float* lamb = lam + (size_t)b * 16 * 128;
  for (int vv = w * 32; vv < w * 32 + 32; ++vv) {
    float acc[16];
#pragma unroll
    for (int kk = 0; kk < 16; ++kk) acc[kk] = 0.f;
#pragma unroll
    for (int ui = 0; ui < 4; ++ui) {
      const float* prow = &pb[(size_t)(128 + vv * 4 + ui) * N_ + n0];
#pragma unroll
      for (int ns = 0; ns < 4; ++ns) {
        float pv = prow[ns * 64 + l];
#pragma unroll
        for (int kk = 0; kk < 16; ++kk)
          acc[kk] += pv * keys_lds[kk * 4 + ui][ns * 64 + l];
      }
    }
#pragma unroll
    for (int kk = 0; kk < 16; ++kk) {
      float vsum = acc[kk];
#pragma unroll
      for (int off = 32; off; off >>= 1) vsum += __shfl_xor(vsum, off);
      if (l == 0) atomicAdd(&lamb[kk * 128 + vv], vsum);
    }
  }
}

// ---------------------------------------------------------------- K4: final fused y_c + y_p
__global__ __launch_bounds__(256) void final_kernel(
    const float* __restrict__ proj, const float* __restrict__ lam,
    const float* __restrict__ emb, float* __restrict__ out) {
  const int n0  = blockIdx.x * 32;
  const int vh  = blockIdx.y;
  const int b   = blockIdx.z;
  const int vv0 = vh * 64;
  const float* pb = proj + (size_t)b * OT * N_;
  const int t = threadIdx.x;

  __shared__ float q_lds[64][32];
  __shared__ float P_lds[256][40];
  __shared__ float A_lds[112][32];
  __shared__ float lam_lds[16][64];
  __shared__ float emb_lds[448];

#pragma unroll
  for (int i = 0; i < 2; ++i) {
    int task = i * 256 + t;
    int r = task >> 3, c4 = (task & 7) * 4;
    *(float4*)&q_lds[r][c4] = *(const float4*)&pb[(size_t)r * N_ + n0 + c4];
  }
  {
    int r = t >> 4, c4 = (t & 15) * 4;
    *(float4*)&lam_lds[r][c4] = *(const float4*)&lam[((size_t)b * 16 + r) * 128 + vv0 + c4];
  }
  for (int i = t; i < 448; i += 256) emb_lds[i] = emb[i];
#pragma unroll
  for (int i = 0; i < 10; ++i) {
    int task = i * 256 + t;
    int r = task / 10;
    int c4g = task - r * 10;
    int gn = n0 - 4 + c4g * 4;
    float4 val = make_float4(0.f, 0.f, 0.f, 0.f);
    if (gn >= 0 && gn < N_)
      val = *(const float4*)&pb[(size_t)(128 + (r >> 6) * 128 + vv0 + (r & 63)) * N_ + gn];
    *(float4*)&P_lds[r][c4g * 4] = val;
  }
  __syncthreads();

#pragma unroll
  for (int i = 0; i < 14; ++i) {
    int task = i * 256 + t;
    int aidx = task % 112;
    int nl   = task / 112;
    int hh = aidx / 28, rem = aidx - hh * 28;
    float s = 0.f;
#pragma unroll
    for (int kk = 0; kk < 16; ++kk)
      s += q_lds[hh * 16 + kk][nl] * emb_lds[kk * 28 + rem];
    A_lds[aidx][nl] = s;
  }
  __syncthreads();

  const int nl = t & 31, pg = t >> 5;
  const int hh = pg >> 1;
  float qreg[16], areg[28];
#pragma unroll
  for (int kk = 0; kk < 16; ++kk) qreg[kk] = q_lds[hh * 16 + kk][nl];
#pragma unroll
  for (int r = 0; r < 28; ++r) areg[r] = A_lds[hh * 28 + r][nl];
  float* ob = out + ((size_t)b * 512 + hh * 128 + vv0) * N_ + n0;
#pragma unroll
  for (int ii = 0; ii < 32; ++ii) {
    int vl = (pg & 1) * 32 + ii;
    float y = 0.f;
#pragma unroll
    for (int kk = 0; kk < 16; ++kk) y += qreg[kk] * lam_lds[kk][vl];
#pragma unroll
    for (int ui = 0; ui < 4; ++ui)
#pragma unroll
      for (int dm = 0; dm < 7; ++dm)
        y += areg[ui * 7 + dm] * P_lds[ui * 64 + vl][nl + dm + 1];
    ob[(size_t)vl * N_ + nl] = y;
  }
}

// ---------------------------------------------------------------- launch
extern "C" void kernel_launch(void* const* d_in, const int* in_sizes, int n_in,
                              void* d_out, int out_size, void* d_ws, size_t ws_size,
                              hipStream_t stream) {
  const float* x   = (const float*)d_in[0];
  const float* Wq  = (const float*)d_in[1];
  const float* gq  = (const float*)d_in[2];
  const float* bq  = (const float*)d_in[3];
  const float* Wk  = (const float*)d_in[4];
  const float* Wv  = (const float*)d_in[5];
  const float* gv  = (const float*)d_in[6];
  const float* bv  = (const float*)d_in[7];
  const float* emb = (const float*)d_in[8];

  float* ws   = (float*)d_ws;
  float* proj = ws;
  __hip_bfloat16* xTb   = (__hip_bfloat16*)(ws + XT_OFF);
  __hip_bfloat16* Wallb = (__hip_bfloat16*)(ws + WB_OFF);
  float* sb   = ws + SB_OFF;
  float* lam  = ws + LAM_OFF;
  float* out  = (float*)d_out;

  hipMemsetAsync(lam, 0, (size_t)B_ * 16 * 128 * sizeof(float), stream);
  pack_kernel<<<dim3(1280), 256, 0, stream>>>(Wq, gq, bq, Wk, Wv, gv, bv, Wallb, sb);
  convert_x<<<dim3(N_ / 64, C_ / 64, B_), 256, 0, stream>>>(x, xTb);
  gemm_mfma<<<dim3(N_ / 128, OT / 128, B_), 256, 0, stream>>>(xTb, Wallb, sb, proj);
  softmax_keys<<<dim3(64, B_), 256, 0, stream>>>(proj);
  lambda_c_kernel<<<dim3(16, B_), 256, 0, stream>>>(proj, lam);
  final_kernel<<<dim3(N_ / 32, 2, B_), 256, 0, stream>>>(proj, lam, emb, out);
}

// Round 3
// 400.185 us; speedup vs baseline: 2.3647x; 1.2963x over previous
//
#include <hip/hip_runtime.h>
#include <hip/hip_bf16.h>

// LambdaConv1d: B=16, C=512, N=4096, h=4, k=16, u=4, v=128, m=7
// R2: lambda_c rewritten (was 211us latency-bound: 1 block/CU, scalar loads,
//     per-256-col shuffle reduces). New: 512 blocks, NC=1024/block with 4x
//     64KB keys re-stage, acc[4][16] in regs, ONE reduce at end, XCD-coherent
//     grid mapping so the 8 vv-group blocks sharing a keys chunk hit same L2.
//   K0  pack:    Wall_bf(640x512 bf16)=[Wq;Wk;Wv], per-row scale/bias f32
//   K0b convert: x (B,C,N) f32 -> xT (B,N,C) bf16  (LDS-tiled transpose)
//   K1  gemm_mfma: proj[b,o,n] = sum_c W[o,c]*xT[b,n,c], epilogue y*s+b (f32)
//   K2  softmax keys rows over N (in-place, f32)
//   K3  lambda_c (f32, rewritten)
//   K4  final fused y_c + y_p (f32)

#define B_  16
#define C_  512
#define N_  4096
#define OT  640   // 64 q rows + 64 key rows + 512 value rows

typedef __bf16 bf16x8 __attribute__((ext_vector_type(8)));
typedef float  f32x4  __attribute__((ext_vector_type(4)));

// ws layout (float offsets)
static constexpr size_t PROJ_ELEMS = (size_t)B_ * OT * N_;           // 41,943,040 f32
static constexpr size_t XT_OFF     = PROJ_ELEMS;                     // bf16 x (B*N*C)
static constexpr size_t WB_OFF     = XT_OFF + ((size_t)B_ * N_ * C_) / 2;
static constexpr size_t SB_OFF     = WB_OFF + ((size_t)OT * C_) / 2;
static constexpr size_t LAM_OFF    = SB_OFF + (size_t)OT * 2;
// total: LAM_OFF + 16*16*128 floats  (~235.7 MB)

__device__ __forceinline__ void load_lds16(const void* g, void* l) {
  __builtin_amdgcn_global_load_lds(
      (const __attribute__((address_space(1))) void*)g,
      (__attribute__((address_space(3))) void*)l, 16, 0, 0);
}

// ---------------------------------------------------------------- K0: pack
__global__ __launch_bounds__(256) void pack_kernel(
    const float* __restrict__ Wq, const float* __restrict__ gq, const float* __restrict__ bq,
    const float* __restrict__ Wk, const float* __restrict__ Wv,
    const float* __restrict__ gv, const float* __restrict__ bv,
    __hip_bfloat16* __restrict__ Wall, float* __restrict__ sb) {
  int idx = blockIdx.x * 256 + threadIdx.x;
  if (idx < OT * C_) {
    int row = idx >> 9;  // /512
    float val;
    if (row < 64)        val = Wq[idx];
    else if (row < 128)  val = Wk[idx - 64 * C_];
    else                 val = Wv[idx - 128 * C_];
    Wall[idx] = __float2bfloat16(val);
  }
  if (idx < OT) {
    const float inv = 0.99999500003749971875f;  // 1/sqrt(1+1e-5)
    float s, bi;
    if (idx < 64)       { s = gq[idx] * inv;       bi = bq[idx]; }
    else if (idx < 128) { s = 1.0f;                bi = 0.0f; }
    else                { s = gv[idx - 128] * inv; bi = bv[idx - 128]; }
    sb[idx * 2]     = s;
    sb[idx * 2 + 1] = bi;
  }
}

// ---------------------------------------------------------------- K0b: x -> xT bf16 (B,N,C)
__global__ __launch_bounds__(256) void convert_x(
    const float* __restrict__ x, __hip_bfloat16* __restrict__ xT) {
  const int n0 = blockIdx.x * 64;
  const int c0 = blockIdx.y * 64;
  const int b  = blockIdx.z;
  __shared__ float tile[64][65];
  const int t = threadIdx.x;
  const int tr = t >> 4, tc4 = (t & 15) * 4;
  const float* xb = x + ((size_t)b * C_ + c0) * N_ + n0;
#pragma unroll
  for (int i = 0; i < 4; ++i) {
    float4 v = *(const float4*)&xb[(size_t)(i * 16 + tr) * N_ + tc4];
    *(float4*)&tile[i * 16 + tr][tc4] = v;
  }
  __syncthreads();
  __hip_bfloat16* ob = xT + ((size_t)b * N_ + n0) * C_ + c0;
#pragma unroll
  for (int i = 0; i < 4; ++i) {
    int rn = i * 16 + tr;
    uint2 pk;
    __hip_bfloat16* ph = (__hip_bfloat16*)&pk;
#pragma unroll
    for (int j = 0; j < 4; ++j) ph[j] = __float2bfloat16(tile[tc4 + j][rn]);
    *(uint2*)&ob[(size_t)rn * C_ + tc4] = pk;
  }
}

// ---------------------------------------------------------------- K1: MFMA proj GEMM
__global__ __launch_bounds__(256) void gemm_mfma(
    const __hip_bfloat16* __restrict__ xT, const __hip_bfloat16* __restrict__ Wb,
    const float* __restrict__ sb, float* __restrict__ proj) {
  const int t = threadIdx.x;
  const int l = t & 63, w = t >> 6;
  const int wr = w >> 1, wc = w & 1;
  const int m0 = blockIdx.y * 128, n0 = blockIdx.x * 128;
  const int b = blockIdx.z;
  const __hip_bfloat16* xb = xT + (size_t)b * N_ * C_;

  __shared__ __hip_bfloat16 Als[128 * 32];  // [m][k] row-major
  __shared__ __hip_bfloat16 Bls[128 * 32];  // [n][k] row-major

  const int srow = w * 16 + (l >> 2);
  const int scol = (l & 3) * 8;
  const __hip_bfloat16* gA = Wb + (size_t)(m0 + srow) * C_ + scol;
  const __hip_bfloat16* gB = xb + (size_t)(n0 + srow) * C_ + scol;
  __hip_bfloat16* lA = &Als[w * 512 + l * 8];
  __hip_bfloat16* lB = &Bls[w * 512 + l * 8];

  const int fr = l & 15;
  const int kg = (l >> 4) * 8;

  f32x4 acc[4][4] = {};

  for (int c0 = 0; c0 < C_; c0 += 32) {
    __syncthreads();
#pragma unroll
    for (int i = 0; i < 2; ++i) {
      load_lds16(gA + (size_t)i * 64 * C_ + c0, lA + i * 2048);
      load_lds16(gB + (size_t)i * 64 * C_ + c0, lB + i * 2048);
    }
    __syncthreads();
    bf16x8 af[4], bfr[4];
#pragma unroll
    for (int m = 0; m < 4; ++m)
      af[m] = *(const bf16x8*)&Als[(size_t)(wr * 64 + m * 16 + fr) * 32 + kg];
#pragma unroll
    for (int n = 0; n < 4; ++n)
      bfr[n] = *(const bf16x8*)&Bls[(size_t)(wc * 64 + n * 16 + fr) * 32 + kg];
#pragma unroll
    for (int m = 0; m < 4; ++m)
#pragma unroll
      for (int n = 0; n < 4; ++n)
        acc[m][n] = __builtin_amdgcn_mfma_f32_16x16x32_bf16(af[m], bfr[n], acc[m][n], 0, 0, 0);
  }

  float* pb = proj + (size_t)b * OT * N_;
  const int rb = (l >> 4) * 4;
#pragma unroll
  for (int m = 0; m < 4; ++m) {
#pragma unroll
    for (int r = 0; r < 4; ++r) {
      int grow = m0 + wr * 64 + m * 16 + rb + r;
      float s = sb[grow * 2], bi = sb[grow * 2 + 1];
#pragma unroll
      for (int n = 0; n < 4; ++n) {
        int gcol = n0 + wc * 64 + n * 16 + fr;
        pb[(size_t)grow * N_ + gcol] = acc[m][n][r] * s + bi;
      }
    }
  }
}

// ---------------------------------------------------------------- K2: keys softmax over N
__global__ __launch_bounds__(256) void softmax_keys(float* __restrict__ proj) {
  const int r = blockIdx.x, b = blockIdx.y;
  float* row = proj + ((size_t)b * OT + 64 + r) * N_;
  const int t = threadIdx.x;
  float4 v[4];
  float mx = -1e30f;
#pragma unroll
  for (int i = 0; i < 4; ++i) {
    v[i] = ((const float4*)row)[t + i * 256];
    mx = fmaxf(mx, fmaxf(fmaxf(v[i].x, v[i].y), fmaxf(v[i].z, v[i].w)));
  }
  __shared__ float red[4];
#pragma unroll
  for (int off = 32; off; off >>= 1) mx = fmaxf(mx, __shfl_xor(mx, off));
  if ((t & 63) == 0) red[t >> 6] = mx;
  __syncthreads();
  mx = fmaxf(fmaxf(red[0], red[1]), fmaxf(red[2], red[3]));
  float sum = 0.f;
#pragma unroll
  for (int i = 0; i < 4; ++i) {
    v[i].x = __expf(v[i].x - mx);
    v[i].y = __expf(v[i].y - mx);
    v[i].z = __expf(v[i].z - mx);
    v[i].w = __expf(v[i].w - mx);
    sum += v[i].x + v[i].y + v[i].z + v[i].w;
  }
  __syncthreads();
#pragma unroll
  for (int off = 32; off; off >>= 1) sum += __shfl_xor(sum, off);
  if ((t & 63) == 0) red[t >> 6] = sum;
  __syncthreads();
  float invs = 1.0f / (red[0] + red[1] + red[2] + red[3]);
#pragma unroll
  for (int i = 0; i < 4; ++i) {
    v[i].x *= invs; v[i].y *= invs; v[i].z *= invs; v[i].w *= invs;
    ((float4*)row)[t + i * 256] = v[i];
  }
}

// ---------------------------------------------------------------- K3: lambda_c (rewritten)
// grid (x = ns + 4*b  [64], y = vg [8]); 512 blocks, 2/CU.
// Blocks sharing a keys chunk (same x, all vg) differ by 64 in linear id
// == 0 mod 8 -> same XCD -> keys chunk L2-resident despite 8x re-read.
// Block: 16 vv (4 waves x 4 vv), NC=1024 n, staged as 4x 64KB keys subchunks.
// acc[4][16] in regs across whole block; single 64-lane butterfly at end.
__global__ __launch_bounds__(256) void lambda_c_kernel(
    const float* __restrict__ proj, float* __restrict__ lam) {
  const int ns = blockIdx.x & 3;
  const int b  = blockIdx.x >> 2;
  const int vg = blockIdx.y;
  const int n0 = ns * 1024;
  const float* pb = proj + (size_t)b * OT * N_;
  __shared__ float keys_lds[64][256];
  const int t = threadIdx.x, l = t & 63, w = t >> 6;
  const int wvv = vg * 16 + w * 4;   // this wave's first vv

  float acc[4][16] = {};

  for (int sc = 0; sc < 4; ++sc) {
    const int nb = n0 + sc * 256;
    __syncthreads();
    // stage keys 64x256 f32 (64KB): 4096 float4 tasks
#pragma unroll
    for (int i = 0; i < 16; ++i) {
      int task = i * 256 + t;
      int r = task >> 6, c4 = (task & 63) * 4;
      *(float4*)&keys_lds[r][c4] = *(const float4*)&pb[(size_t)(64 + r) * N_ + nb + c4];
    }
    __syncthreads();
#pragma unroll
    for (int ui = 0; ui < 4; ++ui) {
      float4 kf[16];
#pragma unroll
      for (int kk = 0; kk < 16; ++kk)
        kf[kk] = *(const float4*)&keys_lds[kk * 4 + ui][l * 4];
#pragma unroll
      for (int vi = 0; vi < 4; ++vi) {
        float4 v = *(const float4*)&pb[(size_t)(128 + (wvv + vi) * 4 + ui) * N_ + nb + l * 4];
#pragma unroll
        for (int kk = 0; kk < 16; ++kk)
          acc[vi][kk] += v.x * kf[kk].x + v.y * kf[kk].y + v.z * kf[kk].z + v.w * kf[kk].w;
      }
    }
  }

  // one butterfly reduce per output
#pragma unroll
  for (int vi = 0; vi < 4; ++vi)
#pragma unroll
    for (int kk = 0; kk < 16; ++kk) {
      float s = acc[vi][kk];
#pragma unroll
      for (int off = 32; off; off >>= 1) s += __shfl_xor(s, off);
      acc[vi][kk] = s;
    }
  if (l == 0) {
    float* lamb = lam + (size_t)b * 16 * 128;
#pragma unroll
    for (int vi = 0; vi < 4; ++vi)
#pragma unroll
      for (int kk = 0; kk < 16; ++kk)
        atomicAdd(&lamb[kk * 128 + wvv + vi], acc[vi][kk]);
  }
}

// ---------------------------------------------------------------- K4: final fused y_c + y_p
__global__ __launch_bounds__(256) void final_kernel(
    const float* __restrict__ proj, const float* __restrict__ lam,
    const float* __restrict__ emb, float* __restrict__ out) {
  const int n0  = blockIdx.x * 32;
  const int vh  = blockIdx.y;
  const int b   = blockIdx.z;
  const int vv0 = vh * 64;
  const float* pb = proj + (size_t)b * OT * N_;
  const int t = threadIdx.x;

  __shared__ float q_lds[64][32];
  __shared__ float P_lds[256][40];
  __shared__ float A_lds[112][32];
  __shared__ float lam_lds[16][64];
  __shared__ float emb_lds[448];

#pragma unroll
  for (int i = 0; i < 2; ++i) {
    int task = i * 256 + t;
    int r = task >> 3, c4 = (task & 7) * 4;
    *(float4*)&q_lds[r][c4] = *(const float4*)&pb[(size_t)r * N_ + n0 + c4];
  }
  {
    int r = t >> 4, c4 = (t & 15) * 4;
    *(float4*)&lam_lds[r][c4] = *(const float4*)&lam[((size_t)b * 16 + r) * 128 + vv0 + c4];
  }
  for (int i = t; i < 448; i += 256) emb_lds[i] = emb[i];
#pragma unroll
  for (int i = 0; i < 10; ++i) {
    int task = i * 256 + t;
    int r = task / 10;
    int c4g = task - r * 10;
    int gn = n0 - 4 + c4g * 4;
    float4 val = make_float4(0.f, 0.f, 0.f, 0.f);
    if (gn >= 0 && gn < N_)
      val = *(const float4*)&pb[(size_t)(128 + (r >> 6) * 128 + vv0 + (r & 63)) * N_ + gn];
    *(float4*)&P_lds[r][c4g * 4] = val;
  }
  __syncthreads();

#pragma unroll
  for (int i = 0; i < 14; ++i) {
    int task = i * 256 + t;
    int aidx = task % 112;
    int nl   = task / 112;
    int hh = aidx / 28, rem = aidx - hh * 28;
    float s = 0.f;
#pragma unroll
    for (int kk = 0; kk < 16; ++kk)
      s += q_lds[hh * 16 + kk][nl] * emb_lds[kk * 28 + rem];
    A_lds[aidx][nl] = s;
  }
  __syncthreads();

  const int nl = t & 31, pg = t >> 5;
  const int hh = pg >> 1;
  float qreg[16], areg[28];
#pragma unroll
  for (int kk = 0; kk < 16; ++kk) qreg[kk] = q_lds[hh * 16 + kk][nl];
#pragma unroll
  for (int r = 0; r < 28; ++r) areg[r] = A_lds[hh * 28 + r][nl];
  float* ob = out + ((size_t)b * 512 + hh * 128 + vv0) * N_ + n0;
#pragma unroll
  for (int ii = 0; ii < 32; ++ii) {
    int vl = (pg & 1) * 32 + ii;
    float y = 0.f;
#pragma unroll
    for (int kk = 0; kk < 16; ++kk) y += qreg[kk] * lam_lds[kk][vl];
#pragma unroll
    for (int ui = 0; ui < 4; ++ui)
#pragma unroll
      for (int dm = 0; dm < 7; ++dm)
        y += areg[ui * 7 + dm] * P_lds[ui * 64 + vl][nl + dm + 1];
    ob[(size_t)vl * N_ + nl] = y;
  }
}

// ---------------------------------------------------------------- launch
extern "C" void kernel_launch(void* const* d_in, const int* in_sizes, int n_in,
                              void* d_out, int out_size, void* d_ws, size_t ws_size,
                              hipStream_t stream) {
  const float* x   = (const float*)d_in[0];
  const float* Wq  = (const float*)d_in[1];
  const float* gq  = (const float*)d_in[2];
  const float* bq  = (const float*)d_in[3];
  const float* Wk  = (const float*)d_in[4];
  const float* Wv  = (const float*)d_in[5];
  const float* gv  = (const float*)d_in[6];
  const float* bv  = (const float*)d_in[7];
  const float* emb = (const float*)d_in[8];

  float* ws   = (float*)d_ws;
  float* proj = ws;
  __hip_bfloat16* xTb   = (__hip_bfloat16*)(ws + XT_OFF);
  __hip_bfloat16* Wallb = (__hip_bfloat16*)(ws + WB_OFF);
  float* sb   = ws + SB_OFF;
  float* lam  = ws + LAM_OFF;
  float* out  = (float*)d_out;

  hipMemsetAsync(lam, 0, (size_t)B_ * 16 * 128 * sizeof(float), stream);
  pack_kernel<<<dim3(1280), 256, 0, stream>>>(Wq, gq, bq, Wk, Wv, gv, bv, Wallb, sb);
  convert_x<<<dim3(N_ / 64, C_ / 64, B_), 256, 0, stream>>>(x, xTb);
  gemm_mfma<<<dim3(N_ / 128, OT / 128, B_), 256, 0, stream>>>(xTb, Wallb, sb, proj);
  softmax_keys<<<dim3(64, B_), 256, 0, stream>>>(proj);
  lambda_c_kernel<<<dim3(64, 8, 1), 256, 0, stream>>>(proj, lam);
  final_kernel<<<dim3(N_ / 32, 2, B_), 256, 0, stream>>>(proj, lam, emb, out);
}

// Round 4
// 354.523 us; speedup vs baseline: 2.6692x; 1.1288x over previous
//
#include <hip/hip_runtime.h>
#include <hip/hip_bf16.h>

// LambdaConv1d: B=16, C=512, N=4096, h=4, k=16, u=4, v=128, m=7
// R3: final stage rewritten around MFMA:
//   Λ[k,vl,nl] = lam[k,vl] (C-seed) + Σ_κ emb[k,κ]·Pcol[κ,(vl,nl)]  (16x16x32 bf16 MFMA,
//     κ=(dm,ui) K-order => lane K-groups contiguous in LDS [vl][n'][ui]; K 28..31 zero on emb side)
//   y[hh,vl,nl] = Σ_k q[hh,k,nl]·Λ[k,vl,nl]   (2 b128 Λ reads + 16 FMA per output)
//   Λ granule-XOR swizzle (G^=(G>>3)&7) for conflict-free b128; LDS 49.7KB -> 3 blocks/CU.
// Other kernels unchanged from R2.

#define B_  16
#define C_  512
#define N_  4096
#define OT  640   // 64 q rows + 64 key rows + 512 value rows

typedef __bf16 bf16x8 __attribute__((ext_vector_type(8)));
typedef float  f32x4  __attribute__((ext_vector_type(4)));

// ws layout (float offsets)
static constexpr size_t PROJ_ELEMS = (size_t)B_ * OT * N_;           // 41,943,040 f32
static constexpr size_t XT_OFF     = PROJ_ELEMS;                     // bf16 x (B*N*C)
static constexpr size_t WB_OFF     = XT_OFF + ((size_t)B_ * N_ * C_) / 2;
static constexpr size_t SB_OFF     = WB_OFF + ((size_t)OT * C_) / 2;
static constexpr size_t LAM_OFF    = SB_OFF + (size_t)OT * 2;
// total: LAM_OFF + 16*16*128 floats  (~235.7 MB)

__device__ __forceinline__ void load_lds16(const void* g, void* l) {
  __builtin_amdgcn_global_load_lds(
      (const __attribute__((address_space(1))) void*)g,
      (__attribute__((address_space(3))) void*)l, 16, 0, 0);
}

__device__ __forceinline__ unsigned short f2bf(float f) {
  __hip_bfloat16 h = __float2bfloat16(f);
  return *(unsigned short*)&h;
}
__device__ __forceinline__ float bf2f(unsigned short u) {
  union { unsigned int i; float f; } c; c.i = ((unsigned int)u) << 16; return c.f;
}

// ---------------------------------------------------------------- K0: pack
__global__ __launch_bounds__(256) void pack_kernel(
    const float* __restrict__ Wq, const float* __restrict__ gq, const float* __restrict__ bq,
    const float* __restrict__ Wk, const float* __restrict__ Wv,
    const float* __restrict__ gv, const float* __restrict__ bv,
    __hip_bfloat16* __restrict__ Wall, float* __restrict__ sb) {
  int idx = blockIdx.x * 256 + threadIdx.x;
  if (idx < OT * C_) {
    int row = idx >> 9;  // /512
    float val;
    if (row < 64)        val = Wq[idx];
    else if (row < 128)  val = Wk[idx - 64 * C_];
    else                 val = Wv[idx - 128 * C_];
    Wall[idx] = __float2bfloat16(val);
  }
  if (idx < OT) {
    const float inv = 0.99999500003749971875f;  // 1/sqrt(1+1e-5)
    float s, bi;
    if (idx < 64)       { s = gq[idx] * inv;       bi = bq[idx]; }
    else if (idx < 128) { s = 1.0f;                bi = 0.0f; }
    else                { s = gv[idx - 128] * inv; bi = bv[idx - 128]; }
    sb[idx * 2]     = s;
    sb[idx * 2 + 1] = bi;
  }
}

// ---------------------------------------------------------------- K0b: x -> xT bf16 (B,N,C)
__global__ __launch_bounds__(256) void convert_x(
    const float* __restrict__ x, __hip_bfloat16* __restrict__ xT) {
  const int n0 = blockIdx.x * 64;
  const int c0 = blockIdx.y * 64;
  const int b  = blockIdx.z;
  __shared__ float tile[64][65];
  const int t = threadIdx.x;
  const int tr = t >> 4, tc4 = (t & 15) * 4;
  const float* xb = x + ((size_t)b * C_ + c0) * N_ + n0;
#pragma unroll
  for (int i = 0; i < 4; ++i) {
    float4 v = *(const float4*)&xb[(size_t)(i * 16 + tr) * N_ + tc4];
    *(float4*)&tile[i * 16 + tr][tc4] = v;
  }
  __syncthreads();
  __hip_bfloat16* ob = xT + ((size_t)b * N_ + n0) * C_ + c0;
#pragma unroll
  for (int i = 0; i < 4; ++i) {
    int rn = i * 16 + tr;
    uint2 pk;
    __hip_bfloat16* ph = (__hip_bfloat16*)&pk;
#pragma unroll
    for (int j = 0; j < 4; ++j) ph[j] = __float2bfloat16(tile[tc4 + j][rn]);
    *(uint2*)&ob[(size_t)rn * C_ + tc4] = pk;
  }
}

// ---------------------------------------------------------------- K1: MFMA proj GEMM
__global__ __launch_bounds__(256) void gemm_mfma(
    const __hip_bfloat16* __restrict__ xT, const __hip_bfloat16* __restrict__ Wb,
    const float* __restrict__ sb, float* __restrict__ proj) {
  const int t = threadIdx.x;
  const int l = t & 63, w = t >> 6;
  const int wr = w >> 1, wc = w & 1;
  const int m0 = blockIdx.y * 128, n0 = blockIdx.x * 128;
  const int b = blockIdx.z;
  const __hip_bfloat16* xb = xT + (size_t)b * N_ * C_;

  __shared__ __hip_bfloat16 Als[128 * 32];  // [m][k] row-major
  __shared__ __hip_bfloat16 Bls[128 * 32];  // [n][k] row-major

  const int srow = w * 16 + (l >> 2);
  const int scol = (l & 3) * 8;
  const __hip_bfloat16* gA = Wb + (size_t)(m0 + srow) * C_ + scol;
  const __hip_bfloat16* gB = xb + (size_t)(n0 + srow) * C_ + scol;
  __hip_bfloat16* lA = &Als[w * 512 + l * 8];
  __hip_bfloat16* lB = &Bls[w * 512 + l * 8];

  const int fr = l & 15;
  const int kg = (l >> 4) * 8;

  f32x4 acc[4][4] = {};

  for (int c0 = 0; c0 < C_; c0 += 32) {
    __syncthreads();
#pragma unroll
    for (int i = 0; i < 2; ++i) {
      load_lds16(gA + (size_t)i * 64 * C_ + c0, lA + i * 2048);
      load_lds16(gB + (size_t)i * 64 * C_ + c0, lB + i * 2048);
    }
    __syncthreads();
    bf16x8 af[4], bfr[4];
#pragma unroll
    for (int m = 0; m < 4; ++m)
      af[m] = *(const bf16x8*)&Als[(size_t)(wr * 64 + m * 16 + fr) * 32 + kg];
#pragma unroll
    for (int n = 0; n < 4; ++n)
      bfr[n] = *(const bf16x8*)&Bls[(size_t)(wc * 64 + n * 16 + fr) * 32 + kg];
#pragma unroll
    for (int m = 0; m < 4; ++m)
#pragma unroll
      for (int n = 0; n < 4; ++n)
        acc[m][n] = __builtin_amdgcn_mfma_f32_16x16x32_bf16(af[m], bfr[n], acc[m][n], 0, 0, 0);
  }

  float* pb = proj + (size_t)b * OT * N_;
  const int rb = (l >> 4) * 4;
#pragma unroll
  for (int m = 0; m < 4; ++m) {
#pragma unroll
    for (int r = 0; r < 4; ++r) {
      int grow = m0 + wr * 64 + m * 16 + rb + r;
      float s = sb[grow * 2], bi = sb[grow * 2 + 1];
#pragma unroll
      for (int n = 0; n < 4; ++n) {
        int gcol = n0 + wc * 64 + n * 16 + fr;
        pb[(size_t)grow * N_ + gcol] = acc[m][n][r] * s + bi;
      }
    }
  }
}

// ---------------------------------------------------------------- K2: keys softmax over N
__global__ __launch_bounds__(256) void softmax_keys(float* __restrict__ proj) {
  const int r = blockIdx.x, b = blockIdx.y;
  float* row = proj + ((size_t)b * OT + 64 + r) * N_;
  const int t = threadIdx.x;
  float4 v[4];
  float mx = -1e30f;
#pragma unroll
  for (int i = 0; i < 4; ++i) {
    v[i] = ((const float4*)row)[t + i * 256];
    mx = fmaxf(mx, fmaxf(fmaxf(v[i].x, v[i].y), fmaxf(v[i].z, v[i].w)));
  }
  __shared__ float red[4];
#pragma unroll
  for (int off = 32; off; off >>= 1) mx = fmaxf(mx, __shfl_xor(mx, off));
  if ((t & 63) == 0) red[t >> 6] = mx;
  __syncthreads();
  mx = fmaxf(fmaxf(red[0], red[1]), fmaxf(red[2], red[3]));
  float sum = 0.f;
#pragma unroll
  for (int i = 0; i < 4; ++i) {
    v[i].x = __expf(v[i].x - mx);
    v[i].y = __expf(v[i].y - mx);
    v[i].z = __expf(v[i].z - mx);
    v[i].w = __expf(v[i].w - mx);
    sum += v[i].x + v[i].y + v[i].z + v[i].w;
  }
  __syncthreads();
#pragma unroll
  for (int off = 32; off; off >>= 1) sum += __shfl_xor(sum, off);
  if ((t & 63) == 0) red[t >> 6] = sum;
  __syncthreads();
  float invs = 1.0f / (red[0] + red[1] + red[2] + red[3]);
#pragma unroll
  for (int i = 0; i < 4; ++i) {
    v[i].x *= invs; v[i].y *= invs; v[i].z *= invs; v[i].w *= invs;
    ((float4*)row)[t + i * 256] = v[i];
  }
}

// ---------------------------------------------------------------- K3: lambda_c (R2)
__global__ __launch_bounds__(256) void lambda_c_kernel(
    const float* __restrict__ proj, float* __restrict__ lam) {
  const int ns = blockIdx.x & 3;
  const int b  = blockIdx.x >> 2;
  const int vg = blockIdx.y;
  const int n0 = ns * 1024;
  const float* pb = proj + (size_t)b * OT * N_;
  __shared__ float keys_lds[64][256];
  const int t = threadIdx.x, l = t & 63, w = t >> 6;
  const int wvv = vg * 16 + w * 4;

  float acc[4][16] = {};

  for (int sc = 0; sc < 4; ++sc) {
    const int nb = n0 + sc * 256;
    __syncthreads();
#pragma unroll
    for (int i = 0; i < 16; ++i) {
      int task = i * 256 + t;
      int r = task >> 6, c4 = (task & 63) * 4;
      *(float4*)&keys_lds[r][c4] = *(const float4*)&pb[(size_t)(64 + r) * N_ + nb + c4];
    }
    __syncthreads();
#pragma unroll
    for (int ui = 0; ui < 4; ++ui) {
      float4 kf[16];
#pragma unroll
      for (int kk = 0; kk < 16; ++kk)
        kf[kk] = *(const float4*)&keys_lds[kk * 4 + ui][l * 4];
#pragma unroll
      for (int vi = 0; vi < 4; ++vi) {
        float4 v = *(const float4*)&pb[(size_t)(128 + (wvv + vi) * 4 + ui) * N_ + nb + l * 4];
#pragma unroll
        for (int kk = 0; kk < 16; ++kk)
          acc[vi][kk] += v.x * kf[kk].x + v.y * kf[kk].y + v.z * kf[kk].z + v.w * kf[kk].w;
      }
    }
  }

#pragma unroll
  for (int vi = 0; vi < 4; ++vi)
#pragma unroll
    for (int kk = 0; kk < 16; ++kk) {
      float s = acc[vi][kk];
#pragma unroll
      for (int off = 32; off; off >>= 1) s += __shfl_xor(s, off);
      acc[vi][kk] = s;
    }
  if (l == 0) {
    float* lamb = lam + (size_t)b * 16 * 128;
#pragma unroll
    for (int vi = 0; vi < 4; ++vi)
#pragma unroll
      for (int kk = 0; kk < 16; ++kk)
        atomicAdd(&lamb[kk * 128 + wvv + vi], acc[vi][kk]);
  }
}

// ---------------------------------------------------------------- K4: final (MFMA Λ)
// grid (N/32=128, 4 vq, B); 256 thr (4 waves). Per block: 4 hh x 32 vl x 32 nl outputs.
// Phase1: stage P bf16 [vl][n' 0..39][ui] (n'=nl+dm, gn=n0+n'-3; 38,39 zero),
//         qT bf16 [nl][72pad] (rows 0..63 = (hh,k)), lamT f32 [vl][16].
// Phase2: 64 MFMAs: Λ[k, (vl,nl)] = mfma(embfrag, Pcol-frag, C=lam[k,vl]).
//         Λ stored bf16, granule-swizzled: page=vl (64 granules x 16B), G'=G^((G>>3)&7).
// Phase3: y[hh,vl,nl] = Σ_k q[hh,k,nl]*Λ[k,vl,nl]; coalesced store.
__global__ __launch_bounds__(256) void final_kernel(
    const float* __restrict__ proj, const float* __restrict__ lam,
    const float* __restrict__ emb, float* __restrict__ out) {
  const int n0  = blockIdx.x * 32;
  const int vq  = blockIdx.y;
  const int b   = blockIdx.z;
  const int vv0 = vq * 32;
  const float* pb = proj + (size_t)b * OT * N_;
  const int t = threadIdx.x, l = t & 63, w = t >> 6;

  __shared__ __hip_bfloat16 P_lds[32][40][4];   // 10,240 B
  __shared__ __hip_bfloat16 qT[32][72];         //  4,608 B (cols 0..63 used)
  __shared__ float lamT[32][16];                //  2,048 B
  __shared__ __hip_bfloat16 Lam[32 * 512];      // 32,768 B  [vl-page][swz granule*8 + k%8]

  // ---- emb fragment (A-operand): lane holds emb[k=l&15][κ=(l>>4)*8+j], κ=(dm*4+ui), 0 for κ>=28
  union { uint4 u; bf16x8 v; } ef;
  {
    unsigned short eh[8];
    const int krow = l & 15, g = l >> 4;
#pragma unroll
    for (int j = 0; j < 8; ++j) {
      int kap = g * 8 + j;
      float val = 0.f;
      if (kap < 28) val = emb[krow * 28 + (kap & 3) * 7 + (kap >> 2)];
      eh[j] = f2bf(val);
    }
    ef.u.x = eh[0] | ((unsigned)eh[1] << 16);
    ef.u.y = eh[2] | ((unsigned)eh[3] << 16);
    ef.u.z = eh[4] | ((unsigned)eh[5] << 16);
    ef.u.w = eh[6] | ((unsigned)eh[7] << 16);
  }

  // ---- Phase 1: staging
  // P: 128 rows (vl,ui) x 40 n'
#pragma unroll
  for (int i = 0; i < 20; ++i) {
    int task = i * 256 + t;               // 5120
    int row = task / 40;
    int np  = task - row * 40;
    int vl = row & 31, ui = row >> 5;
    int gn = n0 + np - 3;
    float val = 0.f;
    if (np < 38 && gn >= 0 && gn < N_)
      val = pb[(size_t)(128 + ui * 128 + vv0 + vl) * N_ + gn];
    P_lds[vl][np][ui] = __float2bfloat16(val);
  }
  // qT: 64 q-rows x 32 nl
#pragma unroll
  for (int i = 0; i < 8; ++i) {
    int task = i * 256 + t;               // 2048
    int qrow = task >> 5, nl = task & 31;
    qT[nl][qrow] = __float2bfloat16(pb[(size_t)qrow * N_ + n0 + nl]);
  }
  // lamT: 16 k x 32 vl
  {
    int kk = t >> 5, vl = t & 31;
    lamT[vl][kk] = lam[((size_t)b * 16 + kk) * 128 + vv0 + vl];
    int kk2 = kk + 8;
    lamT[vl][kk2] = lam[((size_t)b * 16 + kk2) * 128 + vv0 + vl];
  }
  __syncthreads();

  // ---- Phase 2: 16 MFMA tiles per wave
  const int fr = l & 15;         // col within tile / k-row for A
  const int g  = l >> 4;         // K-group
  const int rb = g * 4;          // C/D row base
#pragma unroll
  for (int mi = 0; mi < 16; ++mi) {
    const int vl_t = w * 8 + (mi >> 1);
    const int nt   = mi & 1;
    const int nlc  = nt * 16 + fr;       // nl col
    // B-frag: 8 bf16 = [vl_t][nlc+2g][0..3],[vl_t][nlc+2g+1][0..3]
    union { uint4 u; bf16x8 v; } bf;
    {
      const uint2 lo = *(const uint2*)&P_lds[vl_t][nlc + 2 * g][0];
      const uint2 hi = *(const uint2*)&P_lds[vl_t][nlc + 2 * g + 1][0];
      bf.u.x = lo.x; bf.u.y = lo.y; bf.u.z = hi.x; bf.u.w = hi.y;
    }
    f32x4 c = *(const f32x4*)&lamT[vl_t][rb];
    f32x4 d = __builtin_amdgcn_mfma_f32_16x16x32_bf16(ef.v, bf.v, c, 0, 0, 0);
    // store Λ rows rb..rb+3 at col (vl_t, nlc), swizzled granule
    int G  = nlc * 2 + (rb >> 3);
    int Gs = G ^ ((G >> 3) & 7);
    int base_h = vl_t * 512 + Gs * 8 + (rb & 4);
    union { uint2 u; unsigned short s[4]; } pk;
    pk.s[0] = f2bf(d[0]); pk.s[1] = f2bf(d[1]);
    pk.s[2] = f2bf(d[2]); pk.s[3] = f2bf(d[3]);
    *(uint2*)&Lam[base_h] = pk.u;
  }
  __syncthreads();

  // ---- Phase 3: y = Σ_k q*Λ
  const int nl = l & 31, h2 = l >> 5, hh = w;
  float qf[16];
  {
    union { bf16x8 v; unsigned short s[8]; } qa, qb;
    qa.v = *(const bf16x8*)&qT[nl][hh * 16];
    qb.v = *(const bf16x8*)&qT[nl][hh * 16 + 8];
#pragma unroll
    for (int j = 0; j < 8; ++j) { qf[j] = bf2f(qa.s[j]); qf[j + 8] = bf2f(qb.s[j]); }
  }
  const int G0s = (nl * 2) ^ (((nl * 2) >> 3) & 7);
  const int G1s = (nl * 2 + 1) ^ (((nl * 2 + 1) >> 3) & 7);
  float* ob = out + ((size_t)b * 512 + hh * 128 + vv0) * N_ + n0;
#pragma unroll
  for (int ii = 0; ii < 16; ++ii) {
    const int vl = ii * 2 + h2;
    union { bf16x8 v; unsigned short s[8]; } la, lb;
    la.v = *(const bf16x8*)&Lam[vl * 512 + G0s * 8];
    lb.v = *(const bf16x8*)&Lam[vl * 512 + G1s * 8];
    float y = 0.f;
#pragma unroll
    for (int j = 0; j < 8; ++j) {
      y += qf[j]     * bf2f(la.s[j]);
      y += qf[j + 8] * bf2f(lb.s[j]);
    }
    ob[(size_t)vl * N_ + nl] = y;
  }
}

// ---------------------------------------------------------------- launch
extern "C" void kernel_launch(void* const* d_in, const int* in_sizes, int n_in,
                              void* d_out, int out_size, void* d_ws, size_t ws_size,
                              hipStream_t stream) {
  const float* x   = (const float*)d_in[0];
  const float* Wq  = (const float*)d_in[1];
  const float* gq  = (const float*)d_in[2];
  const float* bq  = (const float*)d_in[3];
  const float* Wk  = (const float*)d_in[4];
  const float* Wv  = (const float*)d_in[5];
  const float* gv  = (const float*)d_in[6];
  const float* bv  = (const float*)d_in[7];
  const float* emb = (const float*)d_in[8];

  float* ws   = (float*)d_ws;
  float* proj = ws;
  __hip_bfloat16* xTb   = (__hip_bfloat16*)(ws + XT_OFF);
  __hip_bfloat16* Wallb = (__hip_bfloat16*)(ws + WB_OFF);
  float* sb   = ws + SB_OFF;
  float* lam  = ws + LAM_OFF;
  float* out  = (float*)d_out;

  hipMemsetAsync(lam, 0, (size_t)B_ * 16 * 128 * sizeof(float), stream);
  pack_kernel<<<dim3(1280), 256, 0, stream>>>(Wq, gq, bq, Wk, Wv, gv, bv, Wallb, sb);
  convert_x<<<dim3(N_ / 64, C_ / 64, B_), 256, 0, stream>>>(x, xTb);
  gemm_mfma<<<dim3(N_ / 128, OT / 128, B_), 256, 0, stream>>>(xTb, Wallb, sb, proj);
  softmax_keys<<<dim3(64, B_), 256, 0, stream>>>(proj);
  lambda_c_kernel<<<dim3(64, 8, 1), 256, 0, stream>>>(proj, lam);
  final_kernel<<<dim3(N_ / 32, 4, B_), 256, 0, stream>>>(proj, lam, emb, out);
}

// Round 5
// 300.285 us; speedup vs baseline: 3.1513x; 1.1806x over previous
//
#include <hip/hip_runtime.h>
#include <hip/hip_bf16.h>

// LambdaConv1d: B=16, C=512, N=4096, h=4, k=16, u=4, v=128, m=7
// R4: final stage — consume MFMA D-frag in registers (no Λ LDS round-trip):
//   tile (vl_t, nt): D = mfma(emb-frag, P-col-frag, C=lam[k,vl]) -> lane(fr,g)
//   holds Λ[k=4g+r][nl=nt*16+fr]; y partial[hh] = Σ_r q[hh,4g+r,nl]·d[r];
//   reduce over g via shfl_xor(16/32); lane-group g stores row hh=g.
//   Deletes Λ buffer + swizzle + Phase-3 loop + qT staging; LDS 49.7->12.3KB.
// Other kernels unchanged from R3.

#define B_  16
#define C_  512
#define N_  4096
#define OT  640   // 64 q rows + 64 key rows + 512 value rows

typedef __bf16 bf16x8 __attribute__((ext_vector_type(8)));
typedef float  f32x4  __attribute__((ext_vector_type(4)));

// ws layout (float offsets)
static constexpr size_t PROJ_ELEMS = (size_t)B_ * OT * N_;           // 41,943,040 f32
static constexpr size_t XT_OFF     = PROJ_ELEMS;                     // bf16 x (B*N*C)
static constexpr size_t WB_OFF     = XT_OFF + ((size_t)B_ * N_ * C_) / 2;
static constexpr size_t SB_OFF     = WB_OFF + ((size_t)OT * C_) / 2;
static constexpr size_t LAM_OFF    = SB_OFF + (size_t)OT * 2;
// total: LAM_OFF + 16*16*128 floats  (~235.7 MB)

__device__ __forceinline__ void load_lds16(const void* g, void* l) {
  __builtin_amdgcn_global_load_lds(
      (const __attribute__((address_space(1))) void*)g,
      (__attribute__((address_space(3))) void*)l, 16, 0, 0);
}

__device__ __forceinline__ unsigned short f2bf(float f) {
  __hip_bfloat16 h = __float2bfloat16(f);
  return *(unsigned short*)&h;
}

// ---------------------------------------------------------------- K0: pack
__global__ __launch_bounds__(256) void pack_kernel(
    const float* __restrict__ Wq, const float* __restrict__ gq, const float* __restrict__ bq,
    const float* __restrict__ Wk, const float* __restrict__ Wv,
    const float* __restrict__ gv, const float* __restrict__ bv,
    __hip_bfloat16* __restrict__ Wall, float* __restrict__ sb) {
  int idx = blockIdx.x * 256 + threadIdx.x;
  if (idx < OT * C_) {
    int row = idx >> 9;  // /512
    float val;
    if (row < 64)        val = Wq[idx];
    else if (row < 128)  val = Wk[idx - 64 * C_];
    else                 val = Wv[idx - 128 * C_];
    Wall[idx] = __float2bfloat16(val);
  }
  if (idx < OT) {
    const float inv = 0.99999500003749971875f;  // 1/sqrt(1+1e-5)
    float s, bi;
    if (idx < 64)       { s = gq[idx] * inv;       bi = bq[idx]; }
    else if (idx < 128) { s = 1.0f;                bi = 0.0f; }
    else                { s = gv[idx - 128] * inv; bi = bv[idx - 128]; }
    sb[idx * 2]     = s;
    sb[idx * 2 + 1] = bi;
  }
}

// ---------------------------------------------------------------- K0b: x -> xT bf16 (B,N,C)
__global__ __launch_bounds__(256) void convert_x(
    const float* __restrict__ x, __hip_bfloat16* __restrict__ xT) {
  const int n0 = blockIdx.x * 64;
  const int c0 = blockIdx.y * 64;
  const int b  = blockIdx.z;
  __shared__ float tile[64][65];
  const int t = threadIdx.x;
  const int tr = t >> 4, tc4 = (t & 15) * 4;
  const float* xb = x + ((size_t)b * C_ + c0) * N_ + n0;
#pragma unroll
  for (int i = 0; i < 4; ++i) {
    float4 v = *(const float4*)&xb[(size_t)(i * 16 + tr) * N_ + tc4];
    *(float4*)&tile[i * 16 + tr][tc4] = v;
  }
  __syncthreads();
  __hip_bfloat16* ob = xT + ((size_t)b * N_ + n0) * C_ + c0;
#pragma unroll
  for (int i = 0; i < 4; ++i) {
    int rn = i * 16 + tr;
    uint2 pk;
    __hip_bfloat16* ph = (__hip_bfloat16*)&pk;
#pragma unroll
    for (int j = 0; j < 4; ++j) ph[j] = __float2bfloat16(tile[tc4 + j][rn]);
    *(uint2*)&ob[(size_t)rn * C_ + tc4] = pk;
  }
}

// ---------------------------------------------------------------- K1: MFMA proj GEMM
__global__ __launch_bounds__(256) void gemm_mfma(
    const __hip_bfloat16* __restrict__ xT, const __hip_bfloat16* __restrict__ Wb,
    const float* __restrict__ sb, float* __restrict__ proj) {
  const int t = threadIdx.x;
  const int l = t & 63, w = t >> 6;
  const int wr = w >> 1, wc = w & 1;
  const int m0 = blockIdx.y * 128, n0 = blockIdx.x * 128;
  const int b = blockIdx.z;
  const __hip_bfloat16* xb = xT + (size_t)b * N_ * C_;

  __shared__ __hip_bfloat16 Als[128 * 32];  // [m][k] row-major
  __shared__ __hip_bfloat16 Bls[128 * 32];  // [n][k] row-major

  const int srow = w * 16 + (l >> 2);
  const int scol = (l & 3) * 8;
  const __hip_bfloat16* gA = Wb + (size_t)(m0 + srow) * C_ + scol;
  const __hip_bfloat16* gB = xb + (size_t)(n0 + srow) * C_ + scol;
  __hip_bfloat16* lA = &Als[w * 512 + l * 8];
  __hip_bfloat16* lB = &Bls[w * 512 + l * 8];

  const int fr = l & 15;
  const int kg = (l >> 4) * 8;

  f32x4 acc[4][4] = {};

  for (int c0 = 0; c0 < C_; c0 += 32) {
    __syncthreads();
#pragma unroll
    for (int i = 0; i < 2; ++i) {
      load_lds16(gA + (size_t)i * 64 * C_ + c0, lA + i * 2048);
      load_lds16(gB + (size_t)i * 64 * C_ + c0, lB + i * 2048);
    }
    __syncthreads();
    bf16x8 af[4], bfr[4];
#pragma unroll
    for (int m = 0; m < 4; ++m)
      af[m] = *(const bf16x8*)&Als[(size_t)(wr * 64 + m * 16 + fr) * 32 + kg];
#pragma unroll
    for (int n = 0; n < 4; ++n)
      bfr[n] = *(const bf16x8*)&Bls[(size_t)(wc * 64 + n * 16 + fr) * 32 + kg];
#pragma unroll
    for (int m = 0; m < 4; ++m)
#pragma unroll
      for (int n = 0; n < 4; ++n)
        acc[m][n] = __builtin_amdgcn_mfma_f32_16x16x32_bf16(af[m], bfr[n], acc[m][n], 0, 0, 0);
  }

  float* pb = proj + (size_t)b * OT * N_;
  const int rb = (l >> 4) * 4;
#pragma unroll
  for (int m = 0; m < 4; ++m) {
#pragma unroll
    for (int r = 0; r < 4; ++r) {
      int grow = m0 + wr * 64 + m * 16 + rb + r;
      float s = sb[grow * 2], bi = sb[grow * 2 + 1];
#pragma unroll
      for (int n = 0; n < 4; ++n) {
        int gcol = n0 + wc * 64 + n * 16 + fr;
        pb[(size_t)grow * N_ + gcol] = acc[m][n][r] * s + bi;
      }
    }
  }
}

// ---------------------------------------------------------------- K2: keys softmax over N
__global__ __launch_bounds__(256) void softmax_keys(float* __restrict__ proj) {
  const int r = blockIdx.x, b = blockIdx.y;
  float* row = proj + ((size_t)b * OT + 64 + r) * N_;
  const int t = threadIdx.x;
  float4 v[4];
  float mx = -1e30f;
#pragma unroll
  for (int i = 0; i < 4; ++i) {
    v[i] = ((const float4*)row)[t + i * 256];
    mx = fmaxf(mx, fmaxf(fmaxf(v[i].x, v[i].y), fmaxf(v[i].z, v[i].w)));
  }
  __shared__ float red[4];
#pragma unroll
  for (int off = 32; off; off >>= 1) mx = fmaxf(mx, __shfl_xor(mx, off));
  if ((t & 63) == 0) red[t >> 6] = mx;
  __syncthreads();
  mx = fmaxf(fmaxf(red[0], red[1]), fmaxf(red[2], red[3]));
  float sum = 0.f;
#pragma unroll
  for (int i = 0; i < 4; ++i) {
    v[i].x = __expf(v[i].x - mx);
    v[i].y = __expf(v[i].y - mx);
    v[i].z = __expf(v[i].z - mx);
    v[i].w = __expf(v[i].w - mx);
    sum += v[i].x + v[i].y + v[i].z + v[i].w;
  }
  __syncthreads();
#pragma unroll
  for (int off = 32; off; off >>= 1) sum += __shfl_xor(sum, off);
  if ((t & 63) == 0) red[t >> 6] = sum;
  __syncthreads();
  float invs = 1.0f / (red[0] + red[1] + red[2] + red[3]);
#pragma unroll
  for (int i = 0; i < 4; ++i) {
    v[i].x *= invs; v[i].y *= invs; v[i].z *= invs; v[i].w *= invs;
    ((float4*)row)[t + i * 256] = v[i];
  }
}

// ---------------------------------------------------------------- K3: lambda_c (R2)
__global__ __launch_bounds__(256) void lambda_c_kernel(
    const float* __restrict__ proj, float* __restrict__ lam) {
  const int ns = blockIdx.x & 3;
  const int b  = blockIdx.x >> 2;
  const int vg = blockIdx.y;
  const int n0 = ns * 1024;
  const float* pb = proj + (size_t)b * OT * N_;
  __shared__ float keys_lds[64][256];
  const int t = threadIdx.x, l = t & 63, w = t >> 6;
  const int wvv = vg * 16 + w * 4;

  float acc[4][16] = {};

  for (int sc = 0; sc < 4; ++sc) {
    const int nb = n0 + sc * 256;
    __syncthreads();
#pragma unroll
    for (int i = 0; i < 16; ++i) {
      int task = i * 256 + t;
      int r = task >> 6, c4 = (task & 63) * 4;
      *(float4*)&keys_lds[r][c4] = *(const float4*)&pb[(size_t)(64 + r) * N_ + nb + c4];
    }
    __syncthreads();
#pragma unroll
    for (int ui = 0; ui < 4; ++ui) {
      float4 kf[16];
#pragma unroll
      for (int kk = 0; kk < 16; ++kk)
        kf[kk] = *(const float4*)&keys_lds[kk * 4 + ui][l * 4];
#pragma unroll
      for (int vi = 0; vi < 4; ++vi) {
        float4 v = *(const float4*)&pb[(size_t)(128 + (wvv + vi) * 4 + ui) * N_ + nb + l * 4];
#pragma unroll
        for (int kk = 0; kk < 16; ++kk)
          acc[vi][kk] += v.x * kf[kk].x + v.y * kf[kk].y + v.z * kf[kk].z + v.w * kf[kk].w;
      }
    }
  }

#pragma unroll
  for (int vi = 0; vi < 4; ++vi)
#pragma unroll
    for (int kk = 0; kk < 16; ++kk) {
      float s = acc[vi][kk];
#pragma unroll
      for (int off = 32; off; off >>= 1) s += __shfl_xor(s, off);
      acc[vi][kk] = s;
    }
  if (l == 0) {
    float* lamb = lam + (size_t)b * 16 * 128;
#pragma unroll
    for (int vi = 0; vi < 4; ++vi)
#pragma unroll
      for (int kk = 0; kk < 16; ++kk)
        atomicAdd(&lamb[kk * 128 + wvv + vi], acc[vi][kk]);
  }
}

// ---------------------------------------------------------------- K4: final (MFMA, in-reg consume)
// grid (N/32=128, 4 vq, B); 256 thr (4 waves). Per block: 4 hh x 32 vl x 32 nl.
// Phase1: P bf16 [vl][np 0..39][ui] (np=n'-(n0-3); 38,39 zero), lamT f32 [vl][16],
//         q preloaded to 32 VGPRs per lane straight from global.
// Phase2: per tile (vl_t,nt): D = mfma(emb, P-col, C=lamT) ->
//         partial[hh] = Sum_r q[hh][r][nt]*d[r]; shfl_xor(16,32) over g; store hh=g.
__global__ __launch_bounds__(256) void final_kernel(
    const float* __restrict__ proj, const float* __restrict__ lam,
    const float* __restrict__ emb, float* __restrict__ out) {
  const int n0  = blockIdx.x * 32;
  const int vq  = blockIdx.y;
  const int b   = blockIdx.z;
  const int vv0 = vq * 32;
  const float* pb = proj + (size_t)b * OT * N_;
  const int t = threadIdx.x, l = t & 63, w = t >> 6;

  __shared__ __hip_bfloat16 P_lds[32][40][4];   // 10,240 B
  __shared__ float lamT[32][16];                //  2,048 B

  const int fr = l & 15;         // A k-row / B nl-col / D col
  const int g  = l >> 4;         // K-group
  const int rb = g * 4;          // D row base (k)

  // ---- emb A-frag: lane holds emb[k=fr][kap=g*8+j], kap=(dm*4+ui), 0 for kap>=28
  union { uint4 u; bf16x8 v; } ef;
  {
    unsigned short eh[8];
#pragma unroll
    for (int j = 0; j < 8; ++j) {
      int kap = g * 8 + j;
      float val = 0.f;
      if (kap < 28) val = emb[fr * 28 + (kap & 3) * 7 + (kap >> 2)];
      eh[j] = f2bf(val);
    }
    ef.u.x = eh[0] | ((unsigned)eh[1] << 16);
    ef.u.y = eh[2] | ((unsigned)eh[3] << 16);
    ef.u.z = eh[4] | ((unsigned)eh[5] << 16);
    ef.u.w = eh[6] | ((unsigned)eh[7] << 16);
  }

  // ---- q preload: q[hh][r][nt] = pb[(hh*16+rb+r)*N + n0+nt*16+fr]
  float qreg[4][4][2];
#pragma unroll
  for (int hh = 0; hh < 4; ++hh)
#pragma unroll
    for (int r = 0; r < 4; ++r)
#pragma unroll
      for (int nt = 0; nt < 2; ++nt)
        qreg[hh][r][nt] = pb[(size_t)(hh * 16 + rb + r) * N_ + n0 + nt * 16 + fr];

  // ---- P staging: 128 rows x 10 float4-windows (aligned at n0-4)
#pragma unroll
  for (int i = 0; i < 5; ++i) {
    int task = i * 256 + t;              // 1280
    int row = task / 10;
    int j4  = task - row * 10;
    int vl = row & 31, ui = row >> 5;
    int gn = n0 - 4 + j4 * 4;
    const float* src = &pb[(size_t)(128 + ui * 128 + vv0 + vl) * N_];
    float4 v4 = make_float4(0.f, 0.f, 0.f, 0.f);
    if (gn >= 0 && gn + 3 < N_) {
      v4 = *(const float4*)&src[gn];
    } else {
      float* pv = &v4.x;
#pragma unroll
      for (int e = 0; e < 4; ++e)
        if (gn + e >= 0 && gn + e < N_) pv[e] = src[gn + e];
    }
#pragma unroll
    for (int e = 0; e < 4; ++e) {
      int np = j4 * 4 + e - 1;
      if (np >= 0) {
        float val = (np < 38) ? (&v4.x)[e] : 0.f;
        P_lds[vl][np][ui] = __float2bfloat16(val);
      }
    }
  }
  // lamT: 16 k x 32 vl
  {
    int kk = t >> 5, vl = t & 31;
    lamT[vl][kk]     = lam[((size_t)b * 16 + kk) * 128 + vv0 + vl];
    lamT[vl][kk + 8] = lam[((size_t)b * 16 + kk + 8) * 128 + vv0 + vl];
  }
  __syncthreads();

  // ---- main: 16 tiles per wave; in-register D-frag consumption
  float* obase = out + ((size_t)b * 512 + g * 128 + vv0) * N_ + n0;
#pragma unroll
  for (int mi = 0; mi < 16; ++mi) {
    const int vl_t = w * 8 + (mi >> 1);
    const int nt   = mi & 1;
    const int nlc  = nt * 16 + fr;
    union { uint4 u; bf16x8 v; } bf;
    {
      const uint2 lo = *(const uint2*)&P_lds[vl_t][nlc + 2 * g][0];
      const uint2 hi = *(const uint2*)&P_lds[vl_t][nlc + 2 * g + 1][0];
      bf.u.x = lo.x; bf.u.y = lo.y; bf.u.z = hi.x; bf.u.w = hi.y;
    }
    f32x4 c = *(const f32x4*)&lamT[vl_t][rb];
    f32x4 d = __builtin_amdgcn_mfma_f32_16x16x32_bf16(ef.v, bf.v, c, 0, 0, 0);
    float p0 = qreg[0][0][nt] * d[0] + qreg[0][1][nt] * d[1] + qreg[0][2][nt] * d[2] + qreg[0][3][nt] * d[3];
    float p1 = qreg[1][0][nt] * d[0] + qreg[1][1][nt] * d[1] + qreg[1][2][nt] * d[2] + qreg[1][3][nt] * d[3];
    float p2 = qreg[2][0][nt] * d[0] + qreg[2][1][nt] * d[1] + qreg[2][2][nt] * d[2] + qreg[2][3][nt] * d[3];
    float p3 = qreg[3][0][nt] * d[0] + qreg[3][1][nt] * d[1] + qreg[3][2][nt] * d[2] + qreg[3][3][nt] * d[3];
    p0 += __shfl_xor(p0, 16); p0 += __shfl_xor(p0, 32);
    p1 += __shfl_xor(p1, 16); p1 += __shfl_xor(p1, 32);
    p2 += __shfl_xor(p2, 16); p2 += __shfl_xor(p2, 32);
    p3 += __shfl_xor(p3, 16); p3 += __shfl_xor(p3, 32);
    float yv = (g == 0) ? p0 : (g == 1) ? p1 : (g == 2) ? p2 : p3;
    obase[(size_t)vl_t * N_ + nlc] = yv;
  }
}

// ---------------------------------------------------------------- launch
extern "C" void kernel_launch(void* const* d_in, const int* in_sizes, int n_in,
                              void* d_out, int out_size, void* d_ws, size_t ws_size,
                              hipStream_t stream) {
  const float* x   = (const float*)d_in[0];
  const float* Wq  = (const float*)d_in[1];
  const float* gq  = (const float*)d_in[2];
  const float* bq  = (const float*)d_in[3];
  const float* Wk  = (const float*)d_in[4];
  const float* Wv  = (const float*)d_in[5];
  const float* gv  = (const float*)d_in[6];
  const float* bv  = (const float*)d_in[7];
  const float* emb = (const float*)d_in[8];

  float* ws   = (float*)d_ws;
  float* proj = ws;
  __hip_bfloat16* xTb   = (__hip_bfloat16*)(ws + XT_OFF);
  __hip_bfloat16* Wallb = (__hip_bfloat16*)(ws + WB_OFF);
  float* sb   = ws + SB_OFF;
  float* lam  = ws + LAM_OFF;
  float* out  = (float*)d_out;

  hipMemsetAsync(lam, 0, (size_t)B_ * 16 * 128 * sizeof(float), stream);
  pack_kernel<<<dim3(1280), 256, 0, stream>>>(Wq, gq, bq, Wk, Wv, gv, bv, Wallb, sb);
  convert_x<<<dim3(N_ / 64, C_ / 64, B_), 256, 0, stream>>>(x, xTb);
  gemm_mfma<<<dim3(N_ / 128, OT / 128, B_), 256, 0, stream>>>(xTb, Wallb, sb, proj);
  softmax_keys<<<dim3(64, B_), 256, 0, stream>>>(proj);
  lambda_c_kernel<<<dim3(64, 8, 1), 256, 0, stream>>>(proj, lam);
  final_kernel<<<dim3(N_ / 32, 4, B_), 256, 0, stream>>>(proj, lam, emb, out);
}